// Round 7
// baseline (391.866 us; speedup 1.0000x reference)
//
#include <hip/hip_runtime.h>

typedef __attribute__((ext_vector_type(8))) short bf16x8;
typedef __attribute__((ext_vector_type(4))) float f32x4;
typedef unsigned short ushort_t;
typedef unsigned int uint32;

#define TILE 64
#define N_EDGES 1600000
#define NT (N_EDGES / TILE) /* 25000 */
#define GRID 512            /* 2 blocks/CU x 256 CU (VGPR-capped occupancy) */

// LDS (ushorts). Weight staging region (used once, then dead) overlaps the
// per-wave h buffers used in the main loop. No col buffer anymore: GEMM1's
// B-fragments are gathered directly from global into registers.
// CSTR=104 / HSTR=136: padded strides -> minimum bank aliasing on all LDS ops.
#define CSTR 104
#define HSTR 136
#define W1_US (128 * CSTR)              /* 13312 us: W1^T staging */
#define W2_US (32 * HSTR)               /* 4352 us:  W2^T staging */
#define WBUF (16 * HSTR)                /* 2176 us per-wave h buffer (aliases dead W1 region) */
#define SMEM_USHORTS (W1_US + W2_US)    /* 17664 us = 35328 B */

__device__ __forceinline__ ushort_t f2bf(float x) {
    uint32 u = __builtin_bit_cast(uint32, x);
    u += 0x7FFFu + ((u >> 16) & 1u);          // round-to-nearest-even
    return (ushort_t)(u >> 16);
}
__device__ __forceinline__ uint32 pack2(float a, float b) {
    return (uint32)f2bf(a) | ((uint32)f2bf(b) << 16);
}
__device__ __forceinline__ bf16x8 pack_bf16x8(f32x4 a, f32x4 b) {
    union { uint32 u[4]; bf16x8 v; } x;
    x.u[0] = pack2(a[0], a[1]);
    x.u[1] = pack2(a[2], a[3]);
    x.u[2] = pack2(b[0], b[1]);
    x.u[3] = pack2(b[2], b[3]);
    return x.v;
}

__global__ __launch_bounds__(256, 2)
void edge_mlp_kernel(const float* __restrict__ edge_feats,
                     const float* __restrict__ node_feats,
                     const int* __restrict__ senders,
                     const int* __restrict__ receivers,
                     const float* __restrict__ W1,
                     const float* __restrict__ b1,
                     const float* __restrict__ W2,
                     const float* __restrict__ b2,
                     float* __restrict__ out)
{
    __shared__ __align__(16) ushort_t smem[SMEM_USHORTS];

    const int tid = threadIdx.x;
    const int l   = tid & 63;
    const int llo = l & 15;              // edge within the wave's 16-edge slice
    const int lhi = l >> 4;              // 8-element k-chunk within a 32-feat source
    const int w   = tid >> 6;            // wave id 0..3

    // ================= one-time: stage weights to LDS, pull frags to REGISTERS =================
    {
        ushort_t* w1t = smem;            // [128][CSTR], k contiguous
        ushort_t* w2t = smem + W1_US;    // [32][HSTR],  n contiguous
        for (int idx = tid; idx < 96 * 128; idx += 256) {
            int k = idx >> 7, n = idx & 127;               // W1[k][n], coalesced read
            w1t[n * CSTR + k] = f2bf(W1[idx]);
        }
        for (int idx = tid; idx < 128 * 32; idx += 256) {
            int n = idx >> 5, o = idx & 31;                // W2[n][o], coalesced read
            w2t[o * HSTR + n] = f2bf(W2[idx]);
        }
    }
    __syncthreads();

    // A-fragment registers (loop-invariant): lane holds W^T[16*i+llo][kk*32+lhi*8 ..+8]
    bf16x8 w1f[8][3];
#pragma unroll
    for (int ni = 0; ni < 8; ++ni)
#pragma unroll
        for (int kk = 0; kk < 3; ++kk)
            w1f[ni][kk] = *reinterpret_cast<const bf16x8*>(
                smem + (ni * 16 + llo) * CSTR + kk * 32 + lhi * 8);
    bf16x8 w2f[2][4];
#pragma unroll
    for (int oi = 0; oi < 2; ++oi)
#pragma unroll
        for (int kk = 0; kk < 4; ++kk)
            w2f[oi][kk] = *reinterpret_cast<const bf16x8*>(
                smem + W1_US + (oi * 16 + llo) * HSTR + kk * 32 + lhi * 8);

    // bias fragments, used as accumulator INIT (C-in of first MFMA)
    f32x4 b1v[8], b2v[2];
#pragma unroll
    for (int ni = 0; ni < 8; ++ni)
        b1v[ni] = *reinterpret_cast<const f32x4*>(b1 + ni * 16 + lhi * 4);
#pragma unroll
    for (int oi = 0; oi < 2; ++oi)
        b2v[oi] = *reinterpret_cast<const f32x4*>(b2 + oi * 16 + lhi * 4);

    __syncthreads();   // weight LDS now dead; region reused as per-wave h buffers

    ushort_t* hbuf = smem + w * WBUF;    // per-wave private h buffer [16][HSTR]

    const long stride = gridDim.x;
    const long last = (long)NT - 1;
    long t = blockIdx.x;

    // ---- software pipeline prologue: B-frag gathers(t) + indices(t+stride) ----
    // Lane (llo,lhi) gathers ITS OWN GEMM1 B-fragment slices: 32B of the edge
    // row + 32B of sender/receiver node rows at float offset lhi*8.
    long eS = t * TILE + w * 16 + llo;
    int si_c = senders[eS], ri_c = receivers[eS];
    f32x4 ea, eb, sa, sb, ra, rb;
    {
        const f32x4* ep_ = reinterpret_cast<const f32x4*>(edge_feats + eS * 32 + lhi * 8);
        ea = ep_[0]; eb = ep_[1];
        const f32x4* sp_ = reinterpret_cast<const f32x4*>(node_feats + (long)si_c * 32 + lhi * 8);
        sa = sp_[0]; sb = sp_[1];
        const f32x4* rp_ = reinterpret_cast<const f32x4*>(node_feats + (long)ri_c * 32 + lhi * 8);
        ra = rp_[0]; rb = rp_[1];
    }
    long ts1 = t + stride; ts1 = ts1 <= last ? ts1 : last;
    long eS1 = ts1 * TILE + w * 16 + llo;
    int si_n = senders[eS1], ri_n = receivers[eS1];

    for (; t < NT; t += stride) {
        // ---- 1. pack current gathers into GEMM1 B-fragments (pure register) ----
        bf16x8 bc0 = pack_bf16x8(ea, eb);   // collected k in [ 0,32): edge feats
        bf16x8 bc1 = pack_bf16x8(sa, sb);   // collected k in [32,64): sender feats
        bf16x8 bc2 = pack_bf16x8(ra, rb);   // collected k in [64,96): receiver feats

        // ---- 2. issue gathers for t+stride (indices prefetched last iteration) ----
        long tn = t + stride; tn = tn <= last ? tn : last;
        {
            long eN = tn * TILE + w * 16 + llo;
            const f32x4* ep_ = reinterpret_cast<const f32x4*>(edge_feats + eN * 32 + lhi * 8);
            ea = ep_[0]; eb = ep_[1];
            const f32x4* sp_ = reinterpret_cast<const f32x4*>(node_feats + (long)si_n * 32 + lhi * 8);
            sa = sp_[0]; sb = sp_[1];
            const f32x4* rp_ = reinterpret_cast<const f32x4*>(node_feats + (long)ri_n * 32 + lhi * 8);
            ra = rp_[0]; rb = rp_[1];
        }
        // ---- 3. issue indices for t+2*stride ----
        long tn2 = t + 2 * stride; tn2 = tn2 <= last ? tn2 : last;
        long eN2 = tn2 * TILE + w * 16 + llo;
        si_n = senders[eN2]; ri_n = receivers[eN2];

        // ---- 4. GEMM1 (all-register): lane -> h[edge=llo][n=ni*16+lhi*4+j] ----
        f32x4 acc1[8];
#pragma unroll
        for (int ni = 0; ni < 8; ++ni) acc1[ni] = b1v[ni];   // bias as C-in
        __builtin_amdgcn_s_setprio(1);
#pragma unroll
        for (int ni = 0; ni < 8; ++ni)
            acc1[ni] = __builtin_amdgcn_mfma_f32_16x16x32_bf16(w1f[ni][0], bc0, acc1[ni], 0, 0, 0);
#pragma unroll
        for (int ni = 0; ni < 8; ++ni)
            acc1[ni] = __builtin_amdgcn_mfma_f32_16x16x32_bf16(w1f[ni][1], bc1, acc1[ni], 0, 0, 0);
#pragma unroll
        for (int ni = 0; ni < 8; ++ni)
            acc1[ni] = __builtin_amdgcn_mfma_f32_16x16x32_bf16(w1f[ni][2], bc2, acc1[ni], 0, 0, 0);
        __builtin_amdgcn_s_setprio(0);

        // ---- epilogue 1: ReLU + pack bf16 -> h[m][n] (wave-local LDS transpose) ----
#pragma unroll
        for (int ni = 0; ni < 8; ++ni) {
            float h0 = fmaxf(acc1[ni][0], 0.f);
            float h1 = fmaxf(acc1[ni][1], 0.f);
            float h2 = fmaxf(acc1[ni][2], 0.f);
            float h3 = fmaxf(acc1[ni][3], 0.f);
            uint2 p;
            p.x = pack2(h0, h1);
            p.y = pack2(h2, h3);
            *reinterpret_cast<uint2*>(hbuf + llo * HSTR + ni * 16 + lhi * 4) = p;
        }

        // ---- 5. GEMM2 (A in regs, B from h LDS): lane -> out[edge=llo][o=oi*16+lhi*4+j] ----
        f32x4 acc2[2];
        acc2[0] = b2v[0];
        acc2[1] = b2v[1];
        const ushort_t* hrow = hbuf + llo * HSTR + lhi * 8;
        __builtin_amdgcn_s_setprio(1);
#pragma unroll
        for (int kk = 0; kk < 4; ++kk) {
            bf16x8 bfrag = *reinterpret_cast<const bf16x8*>(hrow + kk * 32);
#pragma unroll
            for (int oi = 0; oi < 2; ++oi)
                acc2[oi] = __builtin_amdgcn_mfma_f32_16x16x32_bf16(w2f[oi][kk], bfrag, acc2[oi], 0, 0, 0);
        }
        __builtin_amdgcn_s_setprio(0);

        // ---- epilogue 2: coalesced dwordx4 store ----
        float* orow = out + (t * TILE + w * 16 + llo) * 32 + lhi * 4;
        *reinterpret_cast<f32x4*>(orow)      = acc2[0];
        *reinterpret_cast<f32x4*>(orow + 16) = acc2[1];
    }
}

extern "C" void kernel_launch(void* const* d_in, const int* in_sizes, int n_in,
                              void* d_out, int out_size, void* d_ws, size_t ws_size,
                              hipStream_t stream) {
    const float* edge_feats = (const float*)d_in[0];
    const float* node_feats = (const float*)d_in[1];
    const int*   senders    = (const int*)d_in[2];
    const int*   receivers  = (const int*)d_in[3];
    const float* W1         = (const float*)d_in[4];
    const float* b1         = (const float*)d_in[5];
    const float* W2         = (const float*)d_in[6];
    const float* b2         = (const float*)d_in[7];
    float* out = (float*)d_out;

    dim3 grid(GRID), block(256);
    hipLaunchKernelGGL(edge_mlp_kernel, grid, block, 0, stream,
                       edge_feats, node_feats, senders, receivers, W1, b1, W2, b2, out);
}